// Round 5
// baseline (112.233 us; speedup 1.0000x reference)
//
#include <hip/hip_runtime.h>
#include <hip/hip_bf16.h>
#include <stdint.h>

// Problem constants
#define BATCH 16
#define IN_CH 64
#define HIN 56
#define WIN_ 56
#define HO 54
#define WO 54
#define P_PER_B (HO*WO)        // 2916
#define P_PAD 2944             // 23 * 128
#define OUT_CH 256
#define KDIM 576               // 64*3*3
#define NPIX (HIN*WIN_)        // 3136
#define XT_PIX 3264            // padded pixel rows per batch (A-region staging overrun)

typedef __attribute__((ext_vector_type(8))) short short8;
typedef __attribute__((ext_vector_type(4))) float f32x4;

__device__ __forceinline__ unsigned short f2bf(float f) {
    unsigned int u = __float_as_uint(f);
    unsigned int r = (u + 0x7fffu + ((u >> 16) & 1u)) >> 16;   // RNE
    return (unsigned short)r;
}

// ---------------- prep kernels ----------------

// One wave per output channel: bf16-convert weight row REORDERED to k' = tap*64 + c
// (tap = kh*3+kw); compute ||w_o||^2 in fp32.
__global__ void prep_weight(const float* __restrict__ w, short* __restrict__ wbf,
                            float* __restrict__ c2) {
    int o = blockIdx.x;
    int lane = threadIdx.x;           // 0..63
    float s = 0.f;
    #pragma unroll
    for (int j = 0; j < 9; ++j) {     // 576 = 9*64
        int k = j * 64 + lane;        // original k = c*9 + tap
        int c = k / 9, tap = k % 9;
        float v = w[o * KDIM + k];
        s += v * v;
        ((unsigned short*)wbf)[o * KDIM + tap * 64 + c] = f2bf(v);
    }
    #pragma unroll
    for (int off = 32; off > 0; off >>= 1) s += __shfl_down(s, off);
    if (lane == 0) c2[o] = s;
}

// NCHW fp32 -> NHWC bf16 transpose (64 pix x 64 ch per block) + fused per-pixel
// channel square-sum s[b, pix]. xT row stride padded to XT_PIX pixels per batch.
__global__ __launch_bounds__(256) void transpose_kernel(
    const float* __restrict__ x, short* __restrict__ xT, float* __restrict__ s) {
    __shared__ short lds[64 * 65];
    __shared__ float red[256];
    const int b    = blockIdx.x / 49;
    const int pix0 = (blockIdx.x % 49) * 64;
    const int tid  = threadIdx.x;
    const int quarter = tid >> 6;
    const int pix  = tid & 63;
    const float* xb = x + (size_t)b * IN_CH * NPIX + pix0 + pix;
    float acc = 0.f;
    #pragma unroll
    for (int it = 0; it < 16; ++it) {
        int c = quarter * 16 + it;
        float v = xb[c * NPIX];               // wave reads 256B contiguous
        acc += v * v;
        lds[pix * 65 + c] = (short)f2bf(v);
    }
    red[tid] = acc;
    __syncthreads();
    const int cs = tid & 63;
    short* xTb = xT + ((size_t)b * XT_PIX + pix0) * 64;
    #pragma unroll
    for (int it = 0; it < 16; ++it) {
        int pixs = quarter * 16 + it;
        xTb[(size_t)pixs * 64 + cs] = lds[pixs * 65 + cs];  // wave writes 128B contiguous
    }
    if (tid < 64)
        s[b * NPIX + pix0 + tid] = red[tid] + red[64 + tid] + red[128 + tid] + red[192 + tid];
}

// w2[b*P_PAD + p] = 3x3 window sum of s  (= ||win_p||^2, fp32)
__global__ void w2_kernel(const float* __restrict__ s, float* __restrict__ w2) {
    int t = blockIdx.x * 256 + threadIdx.x;
    if (t >= BATCH * P_PER_B) return;
    int b = t / P_PER_B, p = t % P_PER_B;
    int oh = p / WO, ow = p % WO;
    const float* sp = s + b * NPIX + oh * WIN_ + ow;
    float acc = 0.f;
    #pragma unroll
    for (int kh = 0; kh < 3; ++kh)
        #pragma unroll
        for (int kw = 0; kw < 3; ++kw)
            acc += sp[kh * WIN_ + kw];
    w2[b * P_PAD + p] = acc;
}

// ---------------- fused im2col GEMM + RBF epilogue ----------------
// Block tile 128(M) x 64(N), 4 waves of 64x32. A pixel-region (352 rows) staged
// to LDS once (XOR-swizzled). B (288 KB total, L1/L2-resident) lives in
// REGISTERS: each wave loads its 32-channel slice's tap-(kt+1) fragments with 4
// global_load_dwordx4 while tap kt's 16 MFMAs run (explicit double-buffer,
// static-indexed in the fully unrolled loop). lds_b is gone and the 9-tap
// K-loop has ZERO barriers -> waves free-run; 2 waves/SIMD cover each other's
// L2/LDS latency. VGPR ~110 under __launch_bounds__(256,2).
// Epilogue: coalesced via [64][132] f32 LDS transpose (reuses lds_a).

#define AS1(p) ((const __attribute__((address_space(1))) void*)(p))
#define AS3(p) ((__attribute__((address_space(3))) void*)(p))

__global__ __launch_bounds__(256, 2) void gemm_rbf(
    const short* __restrict__ xT, const short* __restrict__ wbf,
    const float* __restrict__ w2, const float* __restrict__ c2,
    float* __restrict__ out) {
    __shared__ __align__(16) short lds_a[352 * 64];      // 45 KB pixel region, swizzled

    const int mt = blockIdx.x;                 // 0..367
    const int b  = mt / 23;
    const int p0 = (mt % 23) * 128;
    const int n0 = blockIdx.y * 64;

    const int tid  = threadIdx.x;
    const int wave = tid >> 6;
    const int lane = tid & 63;
    const int r16  = lane & 15;
    const int quad = lane >> 4;
    const int wm = (wave >> 1) * 64;           // 0 or 64
    const int wn = (wave & 1) * 32;            // 0 or 32

    const int oh_base  = p0 / WO;
    const int ihw_base = oh_base * WIN_;

    // staging lane mapping: 8 lanes per 128-B row, 16 B per lane.
    // physical chunk (lane&7) of lds row r holds logical chunk (lane&7)^(r&7).
    const int srow = lane >> 3;                // 0..7
    const int scx  = (lane & 7) ^ srow;        // pre-swizzled source chunk

    // ---- A-region staging (ONCE): 352 rows from xT, contiguous pixels ----
    const short* aSrc = xT + ((size_t)b * XT_PIX + ihw_base + srow) * 64 + scx * 8;
    #pragma unroll
    for (int i = 0; i < 11; ++i) {             // 4 waves x 11 instrs x 8 rows = 352
        int rb8 = (wave * 11 + i) * 8;
        __builtin_amdgcn_global_load_lds(AS1(aSrc + (size_t)rb8 * 64),
                                         AS3(lds_a + rb8 * 64), 16, 0, 0);
    }

    // per-fragment-row pixel index relative to the staged region (pad rows clamped;
    // their D rows are discarded in the store phase)
    int ihw_rel[4];
    #pragma unroll
    for (int ms = 0; ms < 4; ++ms) {
        int p = p0 + wm + ms * 16 + r16;
        if (p > P_PER_B - 1) p = P_PER_B - 1;
        int oh = p / WO, ow = p - oh * WO;
        ihw_rel[ms] = oh * WIN_ + ow - ihw_base;   // 0..221
    }

    // B fragment base pointers (global -> register): ns in {0,1}
    const short* wp[2];
    #pragma unroll
    for (int ns = 0; ns < 2; ++ns)
        wp[ns] = wbf + (size_t)(n0 + wn + ns * 16 + r16) * KDIM + quad * 8;

    f32x4 acc[4][2];
    #pragma unroll
    for (int i = 0; i < 4; ++i)
        #pragma unroll
        for (int j = 0; j < 2; ++j)
            acc[i][j] = (f32x4){0.f, 0.f, 0.f, 0.f};

    // B register double-buffer [buf][ns][ks]; kt is compile-time in the
    // unrolled loop so all indices are static (no scratch).
    short8 breg[2][2][2];
    #pragma unroll
    for (int ns = 0; ns < 2; ++ns)
        #pragma unroll
        for (int ks = 0; ks < 2; ++ks)
            breg[0][ns][ks] = *(const short8*)(wp[ns] + ks * 32);   // tap 0

    __syncthreads();                           // A region resident (drains vmcnt)

    constexpr int dtab_l[9] = {0, 1, 2, 56, 57, 58, 112, 113, 114};  // kh*56+kw
    #pragma unroll
    for (int kt = 0; kt < 9; ++kt) {
        if (kt < 8) {                          // prefetch next tap's B into regs
            #pragma unroll
            for (int ns = 0; ns < 2; ++ns)
                #pragma unroll
                for (int ks = 0; ks < 2; ++ks)
                    breg[(kt + 1) & 1][ns][ks] =
                        *(const short8*)(wp[ns] + (kt + 1) * 64 + ks * 32);
        }
        const int dt = dtab_l[kt];
        #pragma unroll
        for (int ks = 0; ks < 2; ++ks) {
            short8 af[4];
            #pragma unroll
            for (int ms = 0; ms < 4; ++ms) {
                int rl = ihw_rel[ms] + dt;     // staged-region row for this tap
                af[ms] = *(const short8*)(lds_a + rl * 64
                                                + (((ks * 4 + quad) ^ (rl & 7)) * 8));
            }
            #pragma unroll
            for (int ms = 0; ms < 4; ++ms)
                #pragma unroll
                for (int ns = 0; ns < 2; ++ns)
                    acc[ms][ns] = __builtin_amdgcn_mfma_f32_16x16x32_bf16(
                        af[ms], breg[kt & 1][ns][ks], acc[ms][ns], 0, 0, 0);
        }
    }

    // ---------------- coalesced RBF epilogue via LDS transpose ----------------
    // All 4 waves dump acc into a padded [64ch][132] f32 tile (reusing lds_a),
    // then all 256 threads stream channel-rows out as contiguous 512-B runs.
    float* lf = (float*)lds_a;                 // 64*132*4 = 33.8 KB <= 45 KB
    const int col  = tid & 31;                 // f32x4 column within 512-B run
    const int rb   = tid >> 5;                 // 0..7: row within pass
    const int pcol = p0 + col * 4;
    const bool pok = (pcol < P_PER_B);         // aligned: P_PER_B % 4 == 0
    f32x4 w2v = *(const f32x4*)(w2 + b * P_PAD + pcol);  // pad region valid mem

    __syncthreads();                           // K-loop LDS reads complete
    #pragma unroll
    for (int ms = 0; ms < 4; ++ms) {
        int pl = wm + ms * 16 + quad * 4;
        #pragma unroll
        for (int ns = 0; ns < 2; ++ns) {
            int od = wn + ns * 16 + r16;       // 0..63 channel within block
            *(f32x4*)(lf + od * 132 + pl) = acc[ms][ns];
        }
    }
    __syncthreads();
    #pragma unroll
    for (int pass = 0; pass < 8; ++pass) {
        int row = pass * 8 + rb;               // 0..63
        int o   = n0 + row;
        f32x4 a = *(const f32x4*)(lf + row * 132 + col * 4);
        float c2o = c2[o];
        f32x4 v;
        #pragma unroll
        for (int r = 0; r < 4; ++r) {
            float d2 = w2v[r] + c2o - 2.0f * a[r];
            d2 = fmaxf(d2, 1e-12f);
            v[r] = __expf(-0.125f * d2);
        }
        if (pok)
            *(f32x4*)(out + ((size_t)(b * OUT_CH + o)) * P_PER_B + pcol) = v;
    }
}

// ---------------- launch ----------------

extern "C" void kernel_launch(void* const* d_in, const int* in_sizes, int n_in,
                              void* d_out, int out_size, void* d_ws, size_t ws_size,
                              hipStream_t stream) {
    const float* x = (const float*)d_in[0];    // [16,64,56,56]
    const float* w = (const float*)d_in[1];    // [256,576]
    float* out = (float*)d_out;                // [16,256,54,54]

    char* ws = (char*)d_ws;
    const size_t wbf_bytes = (size_t)OUT_CH * KDIM * 2;            // 294,912
    const size_t c2_bytes  = 1024;                                 // OUT_CH*4
    const size_t w2_bytes  = (size_t)BATCH * P_PAD * 4;            // 188,416
    const size_t s_bytes   = (size_t)BATCH * NPIX * 4;             // 200,704
    short* wbf = (short*)ws;
    float* c2  = (float*)(ws + wbf_bytes);
    float* w2  = (float*)(ws + wbf_bytes + c2_bytes);
    float* s   = (float*)(ws + wbf_bytes + c2_bytes + w2_bytes);
    short* xT  = (short*)(ws + wbf_bytes + c2_bytes + w2_bytes + s_bytes);  // 6.68 MB

    hipLaunchKernelGGL(prep_weight, dim3(OUT_CH), dim3(64), 0, stream, w, wbf, c2);
    hipLaunchKernelGGL(transpose_kernel, dim3(16 * 49), dim3(256), 0, stream, x, xT, s);
    hipLaunchKernelGGL(w2_kernel, dim3((BATCH * P_PER_B + 255) / 256), dim3(256), 0, stream, s, w2);
    hipLaunchKernelGGL(gemm_rbf, dim3(23 * BATCH, 4), dim3(256), 0, stream,
                       xT, wbf, w2, c2, out);
}

// Round 6
// 104.371 us; speedup vs baseline: 1.0753x; 1.0753x over previous
//
#include <hip/hip_runtime.h>
#include <hip/hip_bf16.h>
#include <stdint.h>

// Problem constants
#define BATCH 16
#define IN_CH 64
#define HIN 56
#define WIN_ 56
#define HO 54
#define WO 54
#define P_PER_B (HO*WO)        // 2916
#define P_PAD 2944             // 23 * 128
#define OUT_CH 256
#define KDIM 576               // 64*3*3
#define NPIX (HIN*WIN_)        // 3136
#define XT_PIX 3264            // padded pixel rows per batch (A-region staging overrun)

typedef __attribute__((ext_vector_type(8))) short short8;
typedef __attribute__((ext_vector_type(4))) float f32x4;

__device__ __forceinline__ unsigned short f2bf(float f) {
    unsigned int u = __float_as_uint(f);
    unsigned int r = (u + 0x7fffu + ((u >> 16) & 1u)) >> 16;   // RNE
    return (unsigned short)r;
}

// ---------------- prep kernels ----------------

// One wave per output channel: bf16-convert weight row into TAP-MAJOR layout
// wbf[tap][o][c] (tap = kh*3+kw) so each tap's 128-channel tile is one
// contiguous 16 KB block; compute ||w_o||^2 in fp32.
__global__ void prep_weight(const float* __restrict__ w, short* __restrict__ wbf,
                            float* __restrict__ c2) {
    int o = blockIdx.x;
    int lane = threadIdx.x;           // 0..63
    float s = 0.f;
    #pragma unroll
    for (int j = 0; j < 9; ++j) {     // 576 = 9*64
        int k = j * 64 + lane;        // original k = c*9 + tap
        int c = k / 9, tap = k % 9;
        float v = w[o * KDIM + k];
        s += v * v;
        ((unsigned short*)wbf)[((size_t)tap * OUT_CH + o) * 64 + c] = f2bf(v);
    }
    #pragma unroll
    for (int off = 32; off > 0; off >>= 1) s += __shfl_down(s, off);
    if (lane == 0) c2[o] = s;
}

// NCHW fp32 -> NHWC bf16 transpose (64 pix x 64 ch per block) + fused per-pixel
// channel square-sum s[b, pix]. xT row stride padded to XT_PIX pixels per batch.
__global__ __launch_bounds__(256) void transpose_kernel(
    const float* __restrict__ x, short* __restrict__ xT, float* __restrict__ s) {
    __shared__ short lds[64 * 65];
    __shared__ float red[256];
    const int b    = blockIdx.x / 49;
    const int pix0 = (blockIdx.x % 49) * 64;
    const int tid  = threadIdx.x;
    const int quarter = tid >> 6;
    const int pix  = tid & 63;
    const float* xb = x + (size_t)b * IN_CH * NPIX + pix0 + pix;
    float acc = 0.f;
    #pragma unroll
    for (int it = 0; it < 16; ++it) {
        int c = quarter * 16 + it;
        float v = xb[c * NPIX];               // wave reads 256B contiguous
        acc += v * v;
        lds[pix * 65 + c] = (short)f2bf(v);
    }
    red[tid] = acc;
    __syncthreads();
    const int cs = tid & 63;
    short* xTb = xT + ((size_t)b * XT_PIX + pix0) * 64;
    #pragma unroll
    for (int it = 0; it < 16; ++it) {
        int pixs = quarter * 16 + it;
        xTb[(size_t)pixs * 64 + cs] = lds[pixs * 65 + cs];  // wave writes 128B contiguous
    }
    if (tid < 64)
        s[b * NPIX + pix0 + tid] = red[tid] + red[64 + tid] + red[128 + tid] + red[192 + tid];
}

// w2[b*P_PAD + p] = 3x3 window sum of s  (= ||win_p||^2, fp32)
__global__ void w2_kernel(const float* __restrict__ s, float* __restrict__ w2) {
    int t = blockIdx.x * 256 + threadIdx.x;
    if (t >= BATCH * P_PER_B) return;
    int b = t / P_PER_B, p = t % P_PER_B;
    int oh = p / WO, ow = p % WO;
    const float* sp = s + b * NPIX + oh * WIN_ + ow;
    float acc = 0.f;
    #pragma unroll
    for (int kh = 0; kh < 3; ++kh)
        #pragma unroll
        for (int kw = 0; kw < 3; ++kw)
            acc += sp[kh * WIN_ + kw];
    w2[b * P_PAD + p] = acc;
}

// ---------------- fused im2col GEMM + RBF epilogue ----------------
// R4's measured-best K-loop (A region staged once; B per-tap 16 KB tile
// double-buffered via global_load_lds; one barrier per tap), now with:
//  * 512 threads / 8 waves (wave tile 64x32): 16 waves/CU at 2 blocks/CU
//    (50% occupancy vs 25%), grid 368 blocks <= 512 resident slots ->
//    single co-resident pass, no sequential block tail.
//  * tap-major wbf: each tap's B tile is contiguous -> staging instrs read
//    1 KB contiguous runs (was 8 scattered 1152-B-strided lines).
// Epilogue: coalesced via [64][132] f32 LDS transpose (reuses lds_a).

#define AS1(p) ((const __attribute__((address_space(1))) void*)(p))
#define AS3(p) ((__attribute__((address_space(3))) void*)(p))

__global__ __launch_bounds__(512, 4) void gemm_rbf(
    const short* __restrict__ xT, const short* __restrict__ wbf,
    const float* __restrict__ w2, const float* __restrict__ c2,
    float* __restrict__ out) {
    __shared__ __align__(16) short lds_a[352 * 64];      // 45 KB pixel region, swizzled
    __shared__ __align__(16) short lds_b[2 * 128 * 64];  // 2 x 16 KB per-tap B tiles

    const int mt = blockIdx.x;                 // 0..367
    const int b  = mt / 23;
    const int p0 = (mt % 23) * 128;
    const int n0 = blockIdx.y * 128;

    const int tid  = threadIdx.x;              // 0..511
    const int wave = tid >> 6;                 // 0..7
    const int lane = tid & 63;
    const int r16  = lane & 15;
    const int quad = lane >> 4;
    const int wm = (wave >> 2) * 64;           // 0 or 64
    const int wn = (wave & 3) * 32;            // 0,32,64,96

    const int oh_base  = p0 / WO;
    const int ihw_base = oh_base * WIN_;

    // staging lane mapping: 8 lanes per 128-B row, 16 B per lane.
    // physical chunk (lane&7) of lds row r holds logical chunk (lane&7)^(r&7).
    const int srow = lane >> 3;                // 0..7
    const int scx  = (lane & 7) ^ srow;        // pre-swizzled source chunk

    // ---- A-region staging (ONCE): 352 rows from xT, contiguous pixels ----
    const short* aSrc = xT + ((size_t)b * XT_PIX + ihw_base + srow) * 64 + scx * 8;
    #pragma unroll
    for (int i = 0; i < 6; ++i) {              // 8 waves x 6 x 8 rows, guard at 352
        int rb8 = (wave * 6 + i) * 8;
        if (rb8 < 352)
            __builtin_amdgcn_global_load_lds(AS1(aSrc + (size_t)rb8 * 64),
                                             AS3(lds_a + rb8 * 64), 16, 0, 0);
    }
    // ---- B staging base (tap-major wbf: [tap][o][c]) ----
    // instr (tap t, i): rows n0 + wave*16 + i*8 .. +7, one contiguous 1 KB run
    const short* gbB = wbf + ((size_t)n0 + wave * 16 + srow) * 64 + scx * 8;
    #pragma unroll
    for (int i = 0; i < 2; ++i)                // tap 0 into buffer 0
        __builtin_amdgcn_global_load_lds(AS1(gbB + (size_t)i * 8 * 64),
                                         AS3(lds_b + (wave * 2 + i) * 512), 16, 0, 0);

    // per-fragment-row pixel index relative to the staged region (pad rows clamped;
    // their D rows are discarded in the store phase)
    int ihw_rel[4];
    #pragma unroll
    for (int ms = 0; ms < 4; ++ms) {
        int p = p0 + wm + ms * 16 + r16;
        if (p > P_PER_B - 1) p = P_PER_B - 1;
        int oh = p / WO, ow = p - oh * WO;
        ihw_rel[ms] = oh * WIN_ + ow - ihw_base;   // 0..221
    }
    const int xq = r16 & 7;                    // B fragment-read swizzle key

    f32x4 acc[4][2];
    #pragma unroll
    for (int i = 0; i < 4; ++i)
        #pragma unroll
        for (int j = 0; j < 2; ++j)
            acc[i][j] = (f32x4){0.f, 0.f, 0.f, 0.f};

    __syncthreads();                           // A region + B tap0 resident

    constexpr int dtab_l[9] = {0, 1, 2, 56, 57, 58, 112, 113, 114};  // kh*56+kw
    #pragma unroll
    for (int kt = 0; kt < 9; ++kt) {
        if (kt < 8) {                          // prefetch next tap's B under MFMA
            short* dstB = lds_b + ((kt + 1) & 1) * (128 * 64);
            #pragma unroll
            for (int i = 0; i < 2; ++i)
                __builtin_amdgcn_global_load_lds(
                    AS1(gbB + ((size_t)(kt + 1) * OUT_CH + i * 8) * 64),
                    AS3(dstB + (wave * 2 + i) * 512), 16, 0, 0);
        }
        const short* lb = lds_b + (kt & 1) * (128 * 64);
        const int dt = dtab_l[kt];
        __builtin_amdgcn_s_setprio(1);
        #pragma unroll
        for (int ks = 0; ks < 2; ++ks) {
            short8 af[4], bfr[2];
            #pragma unroll
            for (int ms = 0; ms < 4; ++ms) {
                int rl = ihw_rel[ms] + dt;     // staged-region row for this tap
                af[ms] = *(const short8*)(lds_a + rl * 64
                                                + (((ks * 4 + quad) ^ (rl & 7)) * 8));
            }
            #pragma unroll
            for (int ns = 0; ns < 2; ++ns)
                bfr[ns] = *(const short8*)(lb + (wn + ns * 16 + r16) * 64
                                              + (((ks * 4 + quad) ^ xq) * 8));
            #pragma unroll
            for (int ms = 0; ms < 4; ++ms)
                #pragma unroll
                for (int ns = 0; ns < 2; ++ns)
                    acc[ms][ns] = __builtin_amdgcn_mfma_f32_16x16x32_bf16(
                        af[ms], bfr[ns], acc[ms][ns], 0, 0, 0);
        }
        __builtin_amdgcn_s_setprio(0);
        if (kt < 8) __syncthreads();           // next B resident; old buf free
    }

    // ---------------- coalesced RBF epilogue via LDS transpose ----------------
    // Two 64-channel chunks; owning waves dump acc into a padded [64][132] f32
    // tile (reusing lds_a); then all 512 threads stream channel-rows out as
    // contiguous 512-B runs.
    float* lf = (float*)lds_a;                 // 64*132*4 = 33.8 KB <= 45 KB
    const int col  = tid & 31;                 // f32x4 column within 512-B run
    const int rowb = tid >> 5;                 // 0..15: row within pass
    const int pcol = p0 + col * 4;
    const bool pok = (pcol < P_PER_B);         // aligned: P_PER_B % 4 == 0
    f32x4 w2v = *(const f32x4*)(w2 + b * P_PAD + pcol);  // pad region valid mem
    const int myChunk = (wave >> 1) & 1;       // which 64-ch chunk this wave owns

    #pragma unroll
    for (int s = 0; s < 2; ++s) {
        __syncthreads();                       // lds_a free / prev chunk consumed
        if (myChunk == s) {
            #pragma unroll
            for (int ms = 0; ms < 4; ++ms) {
                int pl = wm + ms * 16 + quad * 4;
                #pragma unroll
                for (int ns = 0; ns < 2; ++ns) {
                    int od = (wave & 1) * 32 + ns * 16 + r16;   // 0..63 in chunk
                    *(f32x4*)(lf + od * 132 + pl) = acc[ms][ns];
                }
            }
        }
        __syncthreads();
        #pragma unroll
        for (int pass = 0; pass < 4; ++pass) {
            int row = pass * 16 + rowb;        // 0..63
            int o   = n0 + s * 64 + row;
            f32x4 a = *(const f32x4*)(lf + row * 132 + col * 4);
            float c2o = c2[o];
            f32x4 v;
            #pragma unroll
            for (int r = 0; r < 4; ++r) {
                float d2 = w2v[r] + c2o - 2.0f * a[r];
                d2 = fmaxf(d2, 1e-12f);
                v[r] = __expf(-0.125f * d2);
            }
            if (pok)
                *(f32x4*)(out + ((size_t)(b * OUT_CH + o)) * P_PER_B + pcol) = v;
        }
    }
}

// ---------------- launch ----------------

extern "C" void kernel_launch(void* const* d_in, const int* in_sizes, int n_in,
                              void* d_out, int out_size, void* d_ws, size_t ws_size,
                              hipStream_t stream) {
    const float* x = (const float*)d_in[0];    // [16,64,56,56]
    const float* w = (const float*)d_in[1];    // [256,576]
    float* out = (float*)d_out;                // [16,256,54,54]

    char* ws = (char*)d_ws;
    const size_t wbf_bytes = (size_t)OUT_CH * KDIM * 2;            // 294,912
    const size_t c2_bytes  = 1024;                                 // OUT_CH*4
    const size_t w2_bytes  = (size_t)BATCH * P_PAD * 4;            // 188,416
    const size_t s_bytes   = (size_t)BATCH * NPIX * 4;             // 200,704
    short* wbf = (short*)ws;
    float* c2  = (float*)(ws + wbf_bytes);
    float* w2  = (float*)(ws + wbf_bytes + c2_bytes);
    float* s   = (float*)(ws + wbf_bytes + c2_bytes + w2_bytes);
    short* xT  = (short*)(ws + wbf_bytes + c2_bytes + w2_bytes + s_bytes);  // 6.68 MB

    hipLaunchKernelGGL(prep_weight, dim3(OUT_CH), dim3(64), 0, stream, w, wbf, c2);
    hipLaunchKernelGGL(transpose_kernel, dim3(16 * 49), dim3(256), 0, stream, x, xT, s);
    hipLaunchKernelGGL(w2_kernel, dim3((BATCH * P_PER_B + 255) / 256), dim3(256), 0, stream, s, w2);
    hipLaunchKernelGGL(gemm_rbf, dim3(23 * BATCH, OUT_CH / 128), dim3(512), 0, stream,
                       xT, wbf, w2, c2, out);
}